// Round 8
// baseline (569.354 us; speedup 1.0000x reference)
//
#include <hip/hip_runtime.h>
#include <hip/hip_fp16.h>

#define BB 32
#define NI 2048
#define NK 64
#define ND 32
#define KD 2048       // caps_n * caps_dim
#define NL 16
#define ITC 8         // i's per conv block
#define NTC (NI/ITC)  // 256
#define RIB 64        // i's per route block
#define NRC (NI/RIB)  // 32
#define RIW (RIB/4)   // 16 i's per wave
#define NPR (NRC*4)   // 128 route partials (per wave, race-free)
#define EPSF 1e-7f

typedef _Float16 f16;
typedef __attribute__((ext_vector_type(8))) _Float16 f16x8;
typedef __attribute__((ext_vector_type(4))) float f32x4;
typedef _Float16 h2 __attribute__((ext_vector_type(2)));
union U4H8 { uint4 u4; h2 h[4]; };

static __device__ __forceinline__ float dot2f(h2 a, h2 b, float c) {
#if __has_builtin(__builtin_amdgcn_fdot2)
  return __builtin_amdgcn_fdot2(a, b, c, false);
#else
  return c + (float)a[0] * (float)b[0] + (float)a[1] * (float)b[1];
#endif
}

static __device__ __forceinline__ h2 pack2(float x, float y) {
  h2 r; r[0] = (_Float16)x; r[1] = (_Float16)y; return r;
}

// K1 (MFMA): u_hat[b][i][cell] = sum_l x[b][i][l] * W[i][cell][l].
// mfma_f32_16x16x32_f16. Packing is convention-robust: A carries x[4g+j] in
// regs j and j+4; B carries W[4g+j] in regs 0-3, zeros in 4-7. MFMA pairs
// A-reg(g,j) with B-reg(g,j) under any (g,j)->k bijection, so the contraction
// sums x[l]*W[l] over l=0..15 regardless of the HW k-order.
// C/D: col = lane&15 (B's n = cell), row = (lane>>4)*4 + j (A's m = b-row).
// grid (NTC, 4): block owns 8 i's x 512 cells; wave owns 128 cells (8 ntiles).
// Fused round-0 partial: pacc accumulates D over the 8 i's (c = 1/64 uniform).
__global__ __launch_bounds__(256) void k_conv(const float* __restrict__ x,
                                              const float* __restrict__ W,
                                              __half* __restrict__ uhat,
                                              __half* __restrict__ part) {
  const int blk = blockIdx.x, cg = blockIdx.y, t = threadIdx.x;
  const int wv = t >> 6, lane = t & 63;
  const int n = lane & 15, g = lane >> 4;
  const int i0 = blk * ITC;

  // A fragments: x[b = h*16+n][i0+ii][l = 4g..4g+3], duplicated in both halves.
  f16x8 A[2][ITC];
  #pragma unroll
  for (int h = 0; h < 2; ++h)
    #pragma unroll
    for (int ii = 0; ii < ITC; ++ii) {
      const f32x4 xv = *(const f32x4*)&x[((size_t)(h * 16 + n) * NI + (i0 + ii)) * NL + 4 * g];
      f16x8 a;
      a[0] = (f16)xv[0]; a[1] = (f16)xv[1]; a[2] = (f16)xv[2]; a[3] = (f16)xv[3];
      a[4] = a[0]; a[5] = a[1]; a[6] = a[2]; a[7] = a[3];
      A[h][ii] = a;
    }

  for (int nt = 0; nt < 8; ++nt) {
    const int cell0 = (cg * 32 + wv * 8 + nt) * 16;
    float pacc0[4] = {0.f, 0.f, 0.f, 0.f};
    float pacc1[4] = {0.f, 0.f, 0.f, 0.f};
    for (int ii = 0; ii < ITC; ++ii) {
      const f32x4 wv4 = *(const f32x4*)&W[((size_t)(i0 + ii) * KD + cell0 + n) * NL + 4 * g];
      f16x8 bf = {0, 0, 0, 0, 0, 0, 0, 0};
      bf[0] = (f16)wv4[0]; bf[1] = (f16)wv4[1]; bf[2] = (f16)wv4[2]; bf[3] = (f16)wv4[3];
      const f32x4 z = {0.f, 0.f, 0.f, 0.f};
      const f32x4 D0 = __builtin_amdgcn_mfma_f32_16x16x32_f16(A[0][ii], bf, z, 0, 0, 0);
      const f32x4 D1 = __builtin_amdgcn_mfma_f32_16x16x32_f16(A[1][ii], bf, z, 0, 0, 0);
      #pragma unroll
      for (int j = 0; j < 4; ++j) {
        const int b0 = 4 * g + j;
        uhat[((size_t)b0 * NI + (i0 + ii)) * KD + cell0 + n] = (__half)D0[j];
        uhat[((size_t)(b0 + 16) * NI + (i0 + ii)) * KD + cell0 + n] = (__half)D1[j];
        pacc0[j] += D0[j];
        pacc1[j] += D1[j];
      }
    }
    #pragma unroll
    for (int j = 0; j < 4; ++j) {
      const int b0 = 4 * g + j;
      part[((size_t)b0 * NTC + blk) * KD + cell0 + n] = (__half)(pacc0[j] * (1.f / 64.f));
      part[((size_t)(b0 + 16) * NTC + blk) * KD + cell0 + n] = (__half)(pacc1[j] * (1.f / 64.f));
    }
  }
}

// Routing round, wave-per-i: lane = k. Lane holds v[k][:] (f16) and sacc[32] f32.
// Softmax over k = 6x shfl_xor across the wave. No LDS, no barriers.
// grid (NRC, BB); block = 4 waves; wave wv handles i = ch*RIB + wv + 4*il.
// Each wave writes its OWN partial slot ch*4+wv (R6/R7 raced on a shared slot).
__global__ __launch_bounds__(256) void k_route(const __half* __restrict__ uhat,
                                               const float* __restrict__ vin,
                                               __half* __restrict__ part) {
  const int ch = blockIdx.x, b = blockIdx.y, t = threadIdx.x;
  const int wv = t >> 6, lane = t & 63;

  h2 vh[16];
  #pragma unroll
  for (int q = 0; q < 4; ++q) {
    const f32x4 v0 = *(const f32x4*)&vin[(size_t)b * KD + lane * ND + 8 * q];
    const f32x4 v1 = *(const f32x4*)&vin[(size_t)b * KD + lane * ND + 8 * q + 4];
    vh[4 * q + 0] = pack2(v0[0], v0[1]); vh[4 * q + 1] = pack2(v0[2], v0[3]);
    vh[4 * q + 2] = pack2(v1[0], v1[1]); vh[4 * q + 3] = pack2(v1[2], v1[3]);
  }

  float sacc[32];
  #pragma unroll
  for (int d = 0; d < 32; ++d) sacc[d] = 0.f;

  const __half* ub = uhat + (size_t)b * NI * KD + lane * ND;
  const int ibase = ch * RIB + wv;
  U4H8 cur[4];
  #pragma unroll
  for (int q = 0; q < 4; ++q)
    cur[q].u4 = *(const uint4*)(ub + (size_t)ibase * KD + 8 * q);

  for (int il = 0; il < RIW; ++il) {
    U4H8 nxt[4];
    if (il + 1 < RIW) {
      const size_t ioff = (size_t)(ibase + 4 * (il + 1)) * KD;
      #pragma unroll
      for (int q = 0; q < 4; ++q)
        nxt[q].u4 = *(const uint4*)(ub + ioff + 8 * q);
    }
    float ag = 0.f;
    #pragma unroll
    for (int q = 0; q < 4; ++q)
      #pragma unroll
      for (int j = 0; j < 4; ++j)
        ag = dot2f(cur[q].h[j], vh[4 * q + j], ag);
    const float e = __expf(ag);   // logits bounded; no max-subtract needed
    float s = e;
    s += __shfl_xor(s, 1);  s += __shfl_xor(s, 2);  s += __shfl_xor(s, 4);
    s += __shfl_xor(s, 8);  s += __shfl_xor(s, 16); s += __shfl_xor(s, 32);
    const float c = e / s;
    #pragma unroll
    for (int q = 0; q < 4; ++q)
      #pragma unroll
      for (int j = 0; j < 4; ++j) {
        sacc[8 * q + 2 * j]     += c * (float)cur[q].h[j][0];
        sacc[8 * q + 2 * j + 1] += c * (float)cur[q].h[j][1];
      }
    #pragma unroll
    for (int q = 0; q < 4; ++q) cur[q] = nxt[q];
  }

  U4H8 o[4];
  #pragma unroll
  for (int q = 0; q < 4; ++q)
    #pragma unroll
    for (int j = 0; j < 4; ++j)
      o[q].h[j] = pack2(sacc[8 * q + 2 * j], sacc[8 * q + 2 * j + 1]);
  __half* pp = part + (((size_t)b * NRC + ch) * 4 + wv) * KD + lane * ND;
  #pragma unroll
  for (int q = 0; q < 4; ++q)
    *(uint4*)(pp + 8 * q) = o[q].u4;
}

// Reduce partials over nch chunks, squash over d=32; optional vprev add
// (round-1 output becomes v0+v1 for the linear-agreement trick).
__global__ __launch_bounds__(256) void k_reduce(const __half* __restrict__ part,
                                                int nch,
                                                const float* __restrict__ vprev,
                                                float* __restrict__ vout) {
  const int g = blockIdx.x, b = blockIdx.y, t = threadIdx.x;
  const int p = g * 256 + t;            // h2-pair index: cells 2p, 2p+1
  const h2* pp = (const h2*)part;
  const size_t base = (size_t)b * nch * (KD / 2) + p;
  float s0 = 0.f, s1 = 0.f;
  for (int ch = 0; ch < nch; ++ch) {
    const h2 v = pp[base + (size_t)ch * (KD / 2)];
    s0 += (float)v[0]; s1 += (float)v[1];
  }
  float sq = s0 * s0 + s1 * s1;
  sq += __shfl_xor(sq, 1); sq += __shfl_xor(sq, 2);
  sq += __shfl_xor(sq, 4); sq += __shfl_xor(sq, 8);
  sq += EPSF;
  const float sc = sqrtf(sq) / (1.f + sq);
  float r0 = s0 * sc, r1 = s1 * sc;
  if (vprev != nullptr) {
    r0 += vprev[(size_t)b * KD + 2 * p];
    r1 += vprev[(size_t)b * KD + 2 * p + 1];
  }
  *(float2*)&vout[(size_t)b * KD + 2 * p] = make_float2(r0, r1);
}

extern "C" void kernel_launch(void* const* d_in, const int* in_sizes, int n_in,
                              void* d_out, int out_size, void* d_ws, size_t ws_size,
                              hipStream_t stream) {
  const float* x = (const float*)d_in[0];   // [32, 2048, 16]
  const float* W = (const float*)d_in[1];   // [2048, 64, 32, 16]
  float* out = (float*)d_out;               // [32, 64, 32]
  char* ws = (char*)d_ws;
  __half* uhat  = (__half*)ws;                                    // 268435456 B
  __half* part0 = (__half*)(ws + 268435456ull);                   // 33554432 B
  __half* partR = part0;   // aliased: part0 fully consumed before first route
  float*  vA    = (float*)(ws + 268435456ull + 33554432ull);
  float*  vB    = vA + (size_t)BB * KD;

  k_conv<<<dim3(NTC, 4), 256, 0, stream>>>(x, W, uhat, part0);
  k_reduce<<<dim3(4, BB), 256, 0, stream>>>(part0, NTC, nullptr, vA);  // vA = v0
  k_route<<<dim3(NRC, BB), 256, 0, stream>>>(uhat, vA, partR);         // u.v0
  k_reduce<<<dim3(4, BB), 256, 0, stream>>>(partR, NPR, vA, vB);       // vB = v0+v1
  k_route<<<dim3(NRC, BB), 256, 0, stream>>>(uhat, vB, partR);         // u.(v0+v1)
  k_reduce<<<dim3(4, BB), 256, 0, stream>>>(partR, NPR, nullptr, out); // out = v2
}

// Round 9
// 289.855 us; speedup vs baseline: 1.9643x; 1.9643x over previous
//
#include <hip/hip_runtime.h>
#include <hip/hip_fp16.h>

#define BB 32
#define NI 2048
#define NK 64
#define ND 32
#define KD 2048       // caps_n * caps_dim
#define NL 16
#define NCH0 64       // round-0 chunks (32 i each)
#define NRC 32        // route chunks (64 i each)
#define EPSF 1e-7f

typedef _Float16 f16;
typedef _Float16 h2 __attribute__((ext_vector_type(2)));
typedef __attribute__((ext_vector_type(4))) float f32x4;
union U4H8 { uint4 u4; h2 h[4]; };
union U2H4 { uint2 u2; h2 h[2]; };

static __device__ __forceinline__ float dot2f(h2 a, h2 b, float c) {
#if __has_builtin(__builtin_amdgcn_fdot2)
  return __builtin_amdgcn_fdot2(a, b, c, false);
#else
  return c + (float)a[0] * (float)b[0] + (float)a[1] * (float)b[1];
#endif
}

static __device__ __forceinline__ float fastrcp(float s) {
#if __has_builtin(__builtin_amdgcn_rcpf)
  return __builtin_amdgcn_rcpf(s);
#else
  return 1.0f / s;
#endif
}

static __device__ __forceinline__ h2 pack2(float x, float y) {
  h2 r; r[0] = (_Float16)x; r[1] = (_Float16)y; return r;
}

// K1 (R1-proven): u_hat[b][i][k][d] f16 = sum_l W[i][k][d][l] * x[b][i][l].
// grid = NI, 512 thr; thread t owns cells 4t..4t+3. W in 64 f32 regs,
// x broadcast from LDS, 8B f16 stores (4KB contiguous per b per block).
__global__ __launch_bounds__(512) void k_uhat(const float* __restrict__ x,
                                              const float* __restrict__ W,
                                              __half* __restrict__ uhat) {
  const int i = blockIdx.x;
  const int t = threadIdx.x;
  __shared__ float xs[BB * NL];  // 512 floats
  {
    const int b = t >> 4, l = t & 15;
    xs[t] = x[((size_t)b * NI + i) * NL + l];
  }
  __syncthreads();
  float w[4][NL];
  const float* Wp = W + (size_t)i * KD * NL + (size_t)t * 4 * NL;
  #pragma unroll
  for (int c = 0; c < 4; ++c)
    #pragma unroll
    for (int q = 0; q < 4; ++q)
      *(float4*)&w[c][q * 4] = *(const float4*)(Wp + c * NL + q * 4);
  __half* up = uhat + (size_t)i * KD + (size_t)t * 4;
  for (int b = 0; b < BB; ++b) {
    float a0 = 0.f, a1 = 0.f, a2 = 0.f, a3 = 0.f;
    #pragma unroll
    for (int l = 0; l < NL; ++l) {
      const float xv = xs[b * NL + l];
      a0 += w[0][l] * xv; a1 += w[1][l] * xv;
      a2 += w[2][l] * xv; a3 += w[3][l] * xv;
    }
    U2H4 o;
    o.h[0] = pack2(a0, a1);
    o.h[1] = pack2(a2, a3);
    *(uint2*)(up + (size_t)b * NI * KD) = o.u2;
  }
}

// K2: round-0 partials (c = 1/64 uniform): part[b][ch][cell] f16.
// grid (NCH0, BB), 256 thr; thread owns 8 cells via 16B loads.
__global__ __launch_bounds__(256) void k_round0(const __half* __restrict__ uhat,
                                                __half* __restrict__ part) {
  const int ch = blockIdx.x, b = blockIdx.y, t = threadIdx.x;
  float acc[8];
  #pragma unroll
  for (int j = 0; j < 8; ++j) acc[j] = 0.f;
  const __half* up = uhat + ((size_t)b * NI + (size_t)ch * 32) * KD + t * 8;
  for (int il = 0; il < 32; ++il) {
    U4H8 u; u.u4 = *(const uint4*)(up + (size_t)il * KD);
    #pragma unroll
    for (int j = 0; j < 4; ++j) {
      acc[2 * j]     += (float)u.h[j][0];
      acc[2 * j + 1] += (float)u.h[j][1];
    }
  }
  U4H8 o;
  #pragma unroll
  for (int j = 0; j < 4; ++j)
    o.h[j] = pack2(acc[2 * j] * (1.f / 64.f), acc[2 * j + 1] * (1.f / 64.f));
  *(uint4*)&part[((size_t)b * NCH0 + ch) * KD + t * 8] = o.u4;
}

// Routing round, wave-per-i with 2-way i-pairing (ILP on the dot/softmax
// chains), no barriers in the main loop. lane = k; lane holds v[k][:] f16 and
// sacc[32] f32. Wave wv at step p handles iA = ch*64 + 8p + wv, iB = iA + 4
// (block reads 8 consecutive i = 32KB contiguous per step). End-of-kernel LDS
// combine -> one partial per block (nch = NRC).
__global__ __launch_bounds__(256) void k_route(const __half* __restrict__ uhat,
                                               const float* __restrict__ vin,
                                               __half* __restrict__ part) {
  const int ch = blockIdx.x, b = blockIdx.y, t = threadIdx.x;
  const int wv = t >> 6, lane = t & 63;

  h2 vh[16];
  #pragma unroll
  for (int q = 0; q < 8; ++q) {
    const f32x4 v = *(const f32x4*)&vin[(size_t)b * KD + lane * ND + 4 * q];
    vh[2 * q]     = pack2(v[0], v[1]);
    vh[2 * q + 1] = pack2(v[2], v[3]);
  }

  float sacc[32];
  #pragma unroll
  for (int d = 0; d < 32; ++d) sacc[d] = 0.f;

  const __half* ub = uhat + (size_t)b * NI * KD + lane * ND;
  const int i00 = ch * 64 + wv;
  U4H8 curA[4], curB[4];
  #pragma unroll
  for (int q = 0; q < 4; ++q) {
    curA[q].u4 = *(const uint4*)(ub + (size_t)i00 * KD + 8 * q);
    curB[q].u4 = *(const uint4*)(ub + (size_t)(i00 + 4) * KD + 8 * q);
  }

  for (int p = 0; p < 8; ++p) {
    U4H8 nxtA[4], nxtB[4];
    if (p + 1 < 8) {
      const size_t oA = (size_t)(i00 + 8 * (p + 1)) * KD;
      #pragma unroll
      for (int q = 0; q < 4; ++q) {
        nxtA[q].u4 = *(const uint4*)(ub + oA + 8 * q);
        nxtB[q].u4 = *(const uint4*)(ub + oA + 4 * KD + 8 * q);
      }
    }
    float agA = 0.f, agB = 0.f;
    #pragma unroll
    for (int q = 0; q < 4; ++q)
      #pragma unroll
      for (int j = 0; j < 4; ++j) {
        agA = dot2f(curA[q].h[j], vh[4 * q + j], agA);
        agB = dot2f(curB[q].h[j], vh[4 * q + j], agB);
      }
    const float eA = __expf(agA);   // logits bounded; no max-subtract needed
    const float eB = __expf(agB);
    float sA = eA, sB = eB;
    sA += __shfl_xor(sA, 1);  sB += __shfl_xor(sB, 1);
    sA += __shfl_xor(sA, 2);  sB += __shfl_xor(sB, 2);
    sA += __shfl_xor(sA, 4);  sB += __shfl_xor(sB, 4);
    sA += __shfl_xor(sA, 8);  sB += __shfl_xor(sB, 8);
    sA += __shfl_xor(sA, 16); sB += __shfl_xor(sB, 16);
    sA += __shfl_xor(sA, 32); sB += __shfl_xor(sB, 32);
    const float cA = eA * fastrcp(sA);
    const float cB = eB * fastrcp(sB);
    #pragma unroll
    for (int q = 0; q < 4; ++q)
      #pragma unroll
      for (int j = 0; j < 4; ++j) {
        sacc[8 * q + 2 * j]     += cA * (float)curA[q].h[j][0]
                                 + cB * (float)curB[q].h[j][0];
        sacc[8 * q + 2 * j + 1] += cA * (float)curA[q].h[j][1]
                                 + cB * (float)curB[q].h[j][1];
      }
    #pragma unroll
    for (int q = 0; q < 4; ++q) { curA[q] = nxtA[q]; curB[q] = nxtB[q]; }
  }

  // Cross-wave combine: red[wv][d][lane] (conflict-free writes), one barrier.
  __shared__ float red[4][ND][64];   // 32 KB
  #pragma unroll
  for (int d = 0; d < ND; ++d) red[wv][d][lane] = sacc[d];
  __syncthreads();
  const int k = t >> 2, d0 = (t & 3) * 8;
  float s[8];
  #pragma unroll
  for (int j = 0; j < 8; ++j)
    s[j] = red[0][d0 + j][k] + red[1][d0 + j][k] +
           red[2][d0 + j][k] + red[3][d0 + j][k];
  U4H8 o;
  #pragma unroll
  for (int j = 0; j < 4; ++j)
    o.h[j] = pack2(s[2 * j], s[2 * j + 1]);
  *(uint4*)&part[((size_t)b * NRC + ch) * KD + 8 * t] = o.u4;
}

// Reduce partials over nch chunks, squash over d=32; optional vprev add
// (round-1 output becomes v0+v1 for the linear-agreement trick).
__global__ __launch_bounds__(256) void k_reduce(const __half* __restrict__ part,
                                                int nch,
                                                const float* __restrict__ vprev,
                                                float* __restrict__ vout) {
  const int g = blockIdx.x, b = blockIdx.y, t = threadIdx.x;
  const int p = g * 256 + t;            // h2-pair index: cells 2p, 2p+1
  const h2* pp = (const h2*)part;
  const size_t base = (size_t)b * nch * (KD / 2) + p;
  float s0 = 0.f, s1 = 0.f;
  for (int ch = 0; ch < nch; ++ch) {
    const h2 v = pp[base + (size_t)ch * (KD / 2)];
    s0 += (float)v[0]; s1 += (float)v[1];
  }
  float sq = s0 * s0 + s1 * s1;
  sq += __shfl_xor(sq, 1); sq += __shfl_xor(sq, 2);
  sq += __shfl_xor(sq, 4); sq += __shfl_xor(sq, 8);
  sq += EPSF;
  const float sc = sqrtf(sq) / (1.f + sq);
  float r0 = s0 * sc, r1 = s1 * sc;
  if (vprev != nullptr) {
    r0 += vprev[(size_t)b * KD + 2 * p];
    r1 += vprev[(size_t)b * KD + 2 * p + 1];
  }
  *(float2*)&vout[(size_t)b * KD + 2 * p] = make_float2(r0, r1);
}

extern "C" void kernel_launch(void* const* d_in, const int* in_sizes, int n_in,
                              void* d_out, int out_size, void* d_ws, size_t ws_size,
                              hipStream_t stream) {
  const float* x = (const float*)d_in[0];   // [32, 2048, 16]
  const float* W = (const float*)d_in[1];   // [2048, 64, 32, 16]
  float* out = (float*)d_out;               // [32, 64, 32]
  char* ws = (char*)d_ws;
  __half* uhat  = (__half*)ws;                                    // 268435456 B
  __half* part0 = (__half*)(ws + 268435456ull);                   // 8388608 B
  __half* partR = (__half*)(ws + 268435456ull + 8388608ull);      // 4194304 B
  float*  vA    = (float*)(ws + 268435456ull + 8388608ull + 4194304ull);
  float*  vB    = vA + (size_t)BB * KD;

  k_uhat<<<NI, 512, 0, stream>>>(x, W, uhat);
  k_round0<<<dim3(NCH0, BB), 256, 0, stream>>>(uhat, part0);
  k_reduce<<<dim3(4, BB), 256, 0, stream>>>(part0, NCH0, nullptr, vA);  // v0
  k_route<<<dim3(NRC, BB), 256, 0, stream>>>(uhat, vA, partR);          // u.v0
  k_reduce<<<dim3(4, BB), 256, 0, stream>>>(partR, NRC, vA, vB);        // v0+v1
  k_route<<<dim3(NRC, BB), 256, 0, stream>>>(uhat, vB, partR);          // u.(v0+v1)
  k_reduce<<<dim3(4, BB), 256, 0, stream>>>(partR, NRC, nullptr, out);  // v2
}

// Round 10
// 289.463 us; speedup vs baseline: 1.9669x; 1.0014x over previous
//
#include <hip/hip_runtime.h>
#include <hip/hip_fp16.h>

#define BB 32
#define NI 2048
#define NK 64
#define ND 32
#define KD 2048       // caps_n * caps_dim
#define NL 16
#define NCH0 64       // round-0 chunks (32 i each)
#define NRC 32        // route chunks (64 i each)
#define EPSF 1e-7f

typedef _Float16 f16;
typedef _Float16 h2 __attribute__((ext_vector_type(2)));
typedef __attribute__((ext_vector_type(4))) float f32x4;
union U4H8 { uint4 u4; h2 h[4]; };
union U2H4 { uint2 u2; h2 h[2]; };

static __device__ __forceinline__ float dot2f(h2 a, h2 b, float c) {
#if __has_builtin(__builtin_amdgcn_fdot2)
  return __builtin_amdgcn_fdot2(a, b, c, false);
#else
  return c + (float)a[0] * (float)b[0] + (float)a[1] * (float)b[1];
#endif
}

static __device__ __forceinline__ float fastrcp(float s) {
#if __has_builtin(__builtin_amdgcn_rcpf)
  return __builtin_amdgcn_rcpf(s);
#else
  return 1.0f / s;
#endif
}

static __device__ __forceinline__ h2 pack2(float x, float y) {
  h2 r; r[0] = (_Float16)x; r[1] = (_Float16)y; return r;
}

// K1: u_hat[b][i][k][d] f16 = sum_l W[i][k][d][l] * x[b][i][l].
// grid = NI, 512 thr; thread t owns cells 4t..4t+3. W tile = 64 f32/thread —
// MUST stay in registers: __launch_bounds__(512, 2) caps occupancy at
// 2 waves/EU -> up to 256 VGPR. (R9: default bounds gave 40 VGPR -> the W
// tile spilled to scratch and was re-read every b-iteration -> 154 us.)
__global__ __launch_bounds__(512, 2) void k_uhat(const float* __restrict__ x,
                                                 const float* __restrict__ W,
                                                 __half* __restrict__ uhat) {
  const int i = blockIdx.x;
  const int t = threadIdx.x;
  __shared__ float xs[BB * NL];  // 512 floats
  {
    const int b = t >> 4, l = t & 15;
    xs[t] = x[((size_t)b * NI + i) * NL + l];
  }
  __syncthreads();
  float w[4][NL];
  const float* Wp = W + (size_t)i * KD * NL + (size_t)t * 4 * NL;
  #pragma unroll
  for (int c = 0; c < 4; ++c)
    #pragma unroll
    for (int q = 0; q < 4; ++q)
      *(float4*)&w[c][q * 4] = *(const float4*)(Wp + c * NL + q * 4);
  __half* up = uhat + (size_t)i * KD + (size_t)t * 4;
  for (int b = 0; b < BB; ++b) {
    float a0 = 0.f, a1 = 0.f, a2 = 0.f, a3 = 0.f;
    #pragma unroll
    for (int l = 0; l < NL; ++l) {
      const float xv = xs[b * NL + l];
      a0 += w[0][l] * xv; a1 += w[1][l] * xv;
      a2 += w[2][l] * xv; a3 += w[3][l] * xv;
    }
    U2H4 o;
    o.h[0] = pack2(a0, a1);
    o.h[1] = pack2(a2, a3);
    *(uint2*)(up + (size_t)b * NI * KD) = o.u2;
  }
}

// K2: round-0 partials (c = 1/64 uniform): part[b][ch][cell] f16.
// grid (NCH0, BB), 256 thr; thread owns 8 cells via 16B loads.
__global__ __launch_bounds__(256) void k_round0(const __half* __restrict__ uhat,
                                                __half* __restrict__ part) {
  const int ch = blockIdx.x, b = blockIdx.y, t = threadIdx.x;
  float acc[8];
  #pragma unroll
  for (int j = 0; j < 8; ++j) acc[j] = 0.f;
  const __half* up = uhat + ((size_t)b * NI + (size_t)ch * 32) * KD + t * 8;
  for (int il = 0; il < 32; ++il) {
    U4H8 u; u.u4 = *(const uint4*)(up + (size_t)il * KD);
    #pragma unroll
    for (int j = 0; j < 4; ++j) {
      acc[2 * j]     += (float)u.h[j][0];
      acc[2 * j + 1] += (float)u.h[j][1];
    }
  }
  U4H8 o;
  #pragma unroll
  for (int j = 0; j < 4; ++j)
    o.h[j] = pack2(acc[2 * j] * (1.f / 64.f), acc[2 * j + 1] * (1.f / 64.f));
  *(uint4*)&part[((size_t)b * NCH0 + ch) * KD + t * 8] = o.u4;
}

// Routing round, wave-per-i with 2-way i-pairing (ILP on the dot/softmax
// chains), no barriers in the main loop. lane = k; lane holds v[k][:] f16 and
// sacc[32] f32. Wave wv at step p handles iA = ch*64 + 8p + wv, iB = iA + 4
// (block reads 8 consecutive i = 32KB contiguous per step). End-of-kernel LDS
// combine -> one partial per block (nch = NRC).
__global__ __launch_bounds__(256) void k_route(const __half* __restrict__ uhat,
                                               const float* __restrict__ vin,
                                               __half* __restrict__ part) {
  const int ch = blockIdx.x, b = blockIdx.y, t = threadIdx.x;
  const int wv = t >> 6, lane = t & 63;

  h2 vh[16];
  #pragma unroll
  for (int q = 0; q < 8; ++q) {
    const f32x4 v = *(const f32x4*)&vin[(size_t)b * KD + lane * ND + 4 * q];
    vh[2 * q]     = pack2(v[0], v[1]);
    vh[2 * q + 1] = pack2(v[2], v[3]);
  }

  float sacc[32];
  #pragma unroll
  for (int d = 0; d < 32; ++d) sacc[d] = 0.f;

  const __half* ub = uhat + (size_t)b * NI * KD + lane * ND;
  const int i00 = ch * 64 + wv;
  U4H8 curA[4], curB[4];
  #pragma unroll
  for (int q = 0; q < 4; ++q) {
    curA[q].u4 = *(const uint4*)(ub + (size_t)i00 * KD + 8 * q);
    curB[q].u4 = *(const uint4*)(ub + (size_t)(i00 + 4) * KD + 8 * q);
  }

  for (int p = 0; p < 8; ++p) {
    U4H8 nxtA[4], nxtB[4];
    if (p + 1 < 8) {
      const size_t oA = (size_t)(i00 + 8 * (p + 1)) * KD;
      #pragma unroll
      for (int q = 0; q < 4; ++q) {
        nxtA[q].u4 = *(const uint4*)(ub + oA + 8 * q);
        nxtB[q].u4 = *(const uint4*)(ub + oA + 4 * KD + 8 * q);
      }
    }
    float agA = 0.f, agB = 0.f;
    #pragma unroll
    for (int q = 0; q < 4; ++q)
      #pragma unroll
      for (int j = 0; j < 4; ++j) {
        agA = dot2f(curA[q].h[j], vh[4 * q + j], agA);
        agB = dot2f(curB[q].h[j], vh[4 * q + j], agB);
      }
    const float eA = __expf(agA);   // logits bounded; no max-subtract needed
    const float eB = __expf(agB);
    float sA = eA, sB = eB;
    sA += __shfl_xor(sA, 1);  sB += __shfl_xor(sB, 1);
    sA += __shfl_xor(sA, 2);  sB += __shfl_xor(sB, 2);
    sA += __shfl_xor(sA, 4);  sB += __shfl_xor(sB, 4);
    sA += __shfl_xor(sA, 8);  sB += __shfl_xor(sB, 8);
    sA += __shfl_xor(sA, 16); sB += __shfl_xor(sB, 16);
    sA += __shfl_xor(sA, 32); sB += __shfl_xor(sB, 32);
    const float cA = eA * fastrcp(sA);
    const float cB = eB * fastrcp(sB);
    #pragma unroll
    for (int q = 0; q < 4; ++q)
      #pragma unroll
      for (int j = 0; j < 4; ++j) {
        sacc[8 * q + 2 * j]     += cA * (float)curA[q].h[j][0]
                                 + cB * (float)curB[q].h[j][0];
        sacc[8 * q + 2 * j + 1] += cA * (float)curA[q].h[j][1]
                                 + cB * (float)curB[q].h[j][1];
      }
    #pragma unroll
    for (int q = 0; q < 4; ++q) { curA[q] = nxtA[q]; curB[q] = nxtB[q]; }
  }

  // Cross-wave combine: red[wv][d][lane] (conflict-free writes), one barrier.
  __shared__ float red[4][ND][64];   // 32 KB
  #pragma unroll
  for (int d = 0; d < ND; ++d) red[wv][d][lane] = sacc[d];
  __syncthreads();
  const int k = t >> 2, d0 = (t & 3) * 8;
  float s[8];
  #pragma unroll
  for (int j = 0; j < 8; ++j)
    s[j] = red[0][d0 + j][k] + red[1][d0 + j][k] +
           red[2][d0 + j][k] + red[3][d0 + j][k];
  U4H8 o;
  #pragma unroll
  for (int j = 0; j < 4; ++j)
    o.h[j] = pack2(s[2 * j], s[2 * j + 1]);
  *(uint4*)&part[((size_t)b * NRC + ch) * KD + 8 * t] = o.u4;
}

// Reduce partials over nch chunks, squash over d=32; optional vprev add
// (round-1 output becomes v0+v1 for the linear-agreement trick).
__global__ __launch_bounds__(256) void k_reduce(const __half* __restrict__ part,
                                                int nch,
                                                const float* __restrict__ vprev,
                                                float* __restrict__ vout) {
  const int g = blockIdx.x, b = blockIdx.y, t = threadIdx.x;
  const int p = g * 256 + t;            // h2-pair index: cells 2p, 2p+1
  const h2* pp = (const h2*)part;
  const size_t base = (size_t)b * nch * (KD / 2) + p;
  float s0 = 0.f, s1 = 0.f;
  for (int ch = 0; ch < nch; ++ch) {
    const h2 v = pp[base + (size_t)ch * (KD / 2)];
    s0 += (float)v[0]; s1 += (float)v[1];
  }
  float sq = s0 * s0 + s1 * s1;
  sq += __shfl_xor(sq, 1); sq += __shfl_xor(sq, 2);
  sq += __shfl_xor(sq, 4); sq += __shfl_xor(sq, 8);
  sq += EPSF;
  const float sc = sqrtf(sq) / (1.f + sq);
  float r0 = s0 * sc, r1 = s1 * sc;
  if (vprev != nullptr) {
    r0 += vprev[(size_t)b * KD + 2 * p];
    r1 += vprev[(size_t)b * KD + 2 * p + 1];
  }
  *(float2*)&vout[(size_t)b * KD + 2 * p] = make_float2(r0, r1);
}

extern "C" void kernel_launch(void* const* d_in, const int* in_sizes, int n_in,
                              void* d_out, int out_size, void* d_ws, size_t ws_size,
                              hipStream_t stream) {
  const float* x = (const float*)d_in[0];   // [32, 2048, 16]
  const float* W = (const float*)d_in[1];   // [2048, 64, 32, 16]
  float* out = (float*)d_out;               // [32, 64, 32]
  char* ws = (char*)d_ws;
  __half* uhat  = (__half*)ws;                                    // 268435456 B
  __half* part0 = (__half*)(ws + 268435456ull);                   // 8388608 B
  __half* partR = (__half*)(ws + 268435456ull + 8388608ull);      // 4194304 B
  float*  vA    = (float*)(ws + 268435456ull + 8388608ull + 4194304ull);
  float*  vB    = vA + (size_t)BB * KD;

  k_uhat<<<NI, 512, 0, stream>>>(x, W, uhat);
  k_round0<<<dim3(NCH0, BB), 256, 0, stream>>>(uhat, part0);
  k_reduce<<<dim3(4, BB), 256, 0, stream>>>(part0, NCH0, nullptr, vA);  // v0
  k_route<<<dim3(NRC, BB), 256, 0, stream>>>(uhat, vA, partR);          // u.v0
  k_reduce<<<dim3(4, BB), 256, 0, stream>>>(partR, NRC, vA, vB);        // v0+v1
  k_route<<<dim3(NRC, BB), 256, 0, stream>>>(uhat, vB, partR);          // u.(v0+v1)
  k_reduce<<<dim3(4, BB), 256, 0, stream>>>(partR, NRC, nullptr, out);  // v2
}